// Round 8
// baseline (24531.972 us; speedup 1.0000x reference)
//
#include <hip/hip_runtime.h>
#include <hip/hip_bf16.h>
#include <stdint.h>

#define EPSV 1e-12f
#define NB 32
#define DD 1024
#define QQ 64
#define EE 384
#define HH 384
#define CH 256    // doc chunk length (steps) per k_xp/k_rec launch

typedef __attribute__((ext_vector_type(4))) float f32x4;
typedef __attribute__((ext_vector_type(8))) __bf16 bf16x8;
typedef __attribute__((ext_vector_type(4))) unsigned short u16x4;
typedef unsigned short u16;

static __device__ __forceinline__ u16 f2bf(float f) {
  union { float f; uint32_t u; } v; v.f = f;
  uint32_t u = v.u;
  return (u16)((u + 0x7fffu + ((u >> 16) & 1u)) >> 16);  // RNE
}

static __device__ __forceinline__ f32x4 MFMA(bf16x8 a, bf16x8 b, f32x4 c) {
  return __builtin_amdgcn_mfma_f32_16x16x32_bf16(a, b, c, 0, 0, 0);
}

static __device__ __forceinline__ bf16x8 ldw8(const float* p) {
  float4 a = *(const float4*)p;
  float4 b = *(const float4*)(p + 4);
  union { u16 e[8]; bf16x8 v; } u;
  u.e[0] = f2bf(a.x); u.e[1] = f2bf(a.y); u.e[2] = f2bf(a.z); u.e[3] = f2bf(a.w);
  u.e[4] = f2bf(b.x); u.e[5] = f2bf(b.y); u.e[6] = f2bf(b.z); u.e[7] = f2bf(b.w);
  return u.v;
}

// ---------------- embedding gather ----------------
__global__ __launch_bounds__(256) void k_emb(const int* __restrict__ doc, const int* __restrict__ qry,
                                             const float* __restrict__ emb, u16* __restrict__ embx) {
  int i = blockIdx.x * 256 + threadIdx.x;
  int row = i / 96, e4 = i - row * 96;
  int tok = (row < NB * DD) ? doc[row] : qry[row - NB * DD];
  float4 v = ((const float4*)(emb + (size_t)tok * EE))[e4];
  u16x4 o; o.x = f2bf(v.x); o.y = f2bf(v.y); o.z = f2bf(v.z); o.w = f2bf(v.w);
  *(u16x4*)(embx + (size_t)row * EE + e4 * 4) = o;
}

// ---------------- xp = x @ W_ih^T + bias, f32, chunked (R4-proven) ----------------
// layout [dir][s_local][gate*384+j][b]
__global__ __launch_bounds__(512, 2) void k_xp(
    const u16* __restrict__ embx, const int* __restrict__ doc_lens, const int* __restrict__ q_lens,
    const float* __restrict__ w_ih_f, const float* __restrict__ b_ih_f, const float* __restrict__ b_hh_f,
    const float* __restrict__ w_ih_b, const float* __restrict__ b_ih_b, const float* __restrict__ b_hh_b,
    float* __restrict__ xpd, float* __restrict__ xpq, int cbase) {
  __shared__ int lensh[32];
  const int gx = blockIdx.x;
  int corpus, d2, jblk, tch;
  if (gx < 48) { corpus = 0; d2 = gx / 24; int rem = gx % 24; jblk = rem / 4; tch = rem % 4; }
  else { corpus = 1; int g2 = gx - 48; d2 = g2 / 6; jblk = g2 % 6; tch = 0; }
  const int T = corpus ? QQ : DD;
  const int* lens = corpus ? q_lens : doc_lens;
  const float* w_ih = d2 ? w_ih_b : w_ih_f;
  const float* b_ih = d2 ? b_ih_b : b_ih_f;
  const float* b_hh = d2 ? b_hh_b : b_hh_f;
  const u16* exb = embx + (corpus ? (size_t)NB * DD * EE : 0);
  float* xpg = corpus ? (xpq + (size_t)d2 * QQ * 36864) : (xpd + (size_t)d2 * CH * 36864);
  const int tid = threadIdx.x;
  if (tid < 32) lensh[tid] = lens[tid];
  __syncthreads();
  const int lane = tid & 63, wv = tid >> 6;
  const int wslot = wv >> 1, mt = wv & 1;
  const int col = lane & 15, khi = lane >> 4;
  const int jg = jblk * 64 + wslot * 16 + col;
  const float br = b_ih[jg] + b_hh[jg];
  const float bz = b_ih[384 + jg] + b_hh[384 + jg];
  const float bn = b_ih[768 + jg];
  bf16x8 Wr[12], Wz[12], Wn[12];
#pragma unroll
  for (int ks = 0; ks < 12; ++ks) {
    Wr[ks] = ldw8(w_ih + (size_t)jg * 384 + ks * 32 + khi * 8);
    Wz[ks] = ldw8(w_ih + (size_t)(384 + jg) * 384 + ks * 32 + khi * 8);
    Wn[ks] = ldw8(w_ih + (size_t)(768 + jg) * 384 + ks * 32 + khi * 8);
  }
  const int b_a = mt * 16 + col;
  const int lenb = lensh[b_a];
  const int bh0 = mt * 16 + khi * 4;
  for (int tt = 0; tt < 64; ++tt) {
    const int s_lc = tch * 64 + tt;
    const int s_g = corpus ? s_lc : (cbase + s_lc);
    const int trow = d2 ? ((s_g < lenb) ? (lenb - 1 - s_g) : s_g) : s_g;
    const u16* ap = exb + ((size_t)b_a * T + trow) * EE + khi * 8;
    bf16x8 A[12];
#pragma unroll
    for (int ks = 0; ks < 12; ++ks) A[ks] = *(const bf16x8*)(ap + ks * 32);
    f32x4 ar{0.f, 0.f, 0.f, 0.f}, az = ar, an = ar;
#pragma unroll
    for (int ks = 0; ks < 12; ++ks) {
      ar = MFMA(A[ks], Wr[ks], ar);
      az = MFMA(A[ks], Wz[ks], az);
      an = MFMA(A[ks], Wn[ks], an);
    }
    float* op = xpg + (size_t)s_lc * 36864 + (size_t)jg * 32 + bh0;
    f32x4 o0{ar[0] + br, ar[1] + br, ar[2] + br, ar[3] + br};
    f32x4 o1{az[0] + bz, az[1] + bz, az[2] + bz, az[3] + bz};
    f32x4 o2{an[0] + bn, an[1] + bn, an[2] + bn, an[3] + bn};
    *(f32x4*)op = o0;
    *(f32x4*)(op + 384 * 32) = o1;
    *(f32x4*)(op + 768 * 32) = o2;
  }
}

// ---------------- BiGRU recurrence: batch-split, W_hh fully in VGPRs, NO cross-WG sync ----------------
// WG = (corpus, dir, batch-half). 12 waves; wave w owns h-dims [w*32, w*32+32) for all 3 gates.
// h (bf16) in LDS double-buffer; per-step sync = one s_barrier. 864 MFMA/step.
__global__ __launch_bounds__(768, 1) void k_rec(
    const float* __restrict__ xpd, const float* __restrict__ xpq,
    const int* __restrict__ doc_lens, const int* __restrict__ q_lens,
    const float* __restrict__ w_hh_f, const float* __restrict__ b_hh_f,
    const float* __restrict__ w_hh_b, const float* __restrict__ b_hh_b,
    u16* __restrict__ doc_h, u16* __restrict__ q_h,
    float* __restrict__ h_state, int cbase, int first) {
  __shared__ u16 hl[2][16][392];   // [buf][batch][j] bf16, padded row (784 B, 16B-aligned)
  __shared__ int lensh[16];
  const int bid = blockIdx.x;
  const int corpus = first ? (bid >> 2) : 0;
  const int dir = (bid >> 1) & 1;
  const int half = bid & 1;
  const int grp = corpus * 2 + dir;
  const int T = corpus ? QQ : DD;
  const int nst = corpus ? QQ : CH;
  const int* lens = corpus ? q_lens : doc_lens;
  const float* w_hh = dir ? w_hh_b : w_hh_f;
  const float* b_hh = dir ? b_hh_b : b_hh_f;
  u16* out = corpus ? q_h : doc_h;
  const float* xpg = corpus ? (xpq + (size_t)dir * QQ * 36864) : (xpd + (size_t)dir * CH * 36864);
  const int tid = threadIdx.x;
  const int wv = tid >> 6, lane = tid & 63;
  const int jl = lane & 15, khi = lane >> 4;
  if (tid < 16) lensh[tid] = lens[half * 16 + tid];

  // ---- W_hh slice into VGPRs: 6 tiles (3 gates x 2 j-subtiles) x 12 k-tiles = 288 VGPR ----
  bf16x8 W[72];
#pragma unroll
  for (int t = 0; t < 6; ++t) {
    const int g = t >> 1, jt = t & 1;
    const int row = g * 384 + wv * 32 + jt * 16 + jl;
#pragma unroll
    for (int kt = 0; kt < 12; ++kt)
      W[t * 12 + kt] = ldw8(w_hh + (size_t)row * 384 + kt * 32 + khi * 8);
  }
  const float bhn0 = b_hh[768 + wv * 32 + jl];
  const float bhn1 = b_hh[768 + wv * 32 + 16 + jl];

  // ---- init h state: hprev f32 regs + hl[0] bf16 ----
  float hprev[2][4];
#pragma unroll
  for (int jt = 0; jt < 2; ++jt)
#pragma unroll
    for (int r = 0; r < 4; ++r) {
      const int bl = khi * 4 + r;
      const int j = wv * 32 + jt * 16 + jl;
      float hs = first ? 0.f : h_state[(size_t)grp * 12288 + (size_t)j * 32 + half * 16 + bl];
      hprev[jt][r] = hs;
      hl[0][bl][j] = f2bf(hs);
    }
  __syncthreads();

  int len4[4];
#pragma unroll
  for (int r = 0; r < 4; ++r) len4[r] = lensh[khi * 4 + r];
  u16* outp = out + (size_t)dir * HH;

  for (int sl = 0; sl < nst; ++sl) {
    const int s = cbase + sl;
    const int p = sl & 1;
    // xp for this step: 6 f32x4 (consumed at gate time; compiler schedules waits)
    const float* xps = xpg + (size_t)sl * 36864;
    f32x4 xpv[6];
#pragma unroll
    for (int t = 0; t < 6; ++t) {
      const int g = t >> 1, jt = t & 1;
      xpv[t] = *(const f32x4*)(xps + ((size_t)(g * 384 + wv * 32 + jt * 16 + jl)) * 32 + half * 16 + khi * 4);
    }
    // 864 MFMA: A = h (16 batches x 384), B = wave's weight slice
    f32x4 acc[6];
#pragma unroll
    for (int t = 0; t < 6; ++t) acc[t] = f32x4{0.f, 0.f, 0.f, 0.f};
#pragma unroll
    for (int kg = 0; kg < 3; ++kg) {
      bf16x8 A[4];
#pragma unroll
      for (int kk = 0; kk < 4; ++kk)
        A[kk] = *(const bf16x8*)&hl[p][jl][(kg * 4 + kk) * 32 + khi * 8];
#pragma unroll
      for (int kk = 0; kk < 4; ++kk)
#pragma unroll
        for (int t = 0; t < 6; ++t)
          acc[t] = MFMA(A[kk], W[t * 12 + kg * 4 + kk], acc[t]);
    }
    // gates (in-lane), h write to other LDS buffer, output store
#pragma unroll
    for (int jt = 0; jt < 2; ++jt) {
      const float bhn = jt ? bhn1 : bhn0;
      const int j = wv * 32 + jt * 16 + jl;
#pragma unroll
      for (int r = 0; r < 4; ++r) {
        const int bl = khi * 4 + r;
        float rg = 1.f / (1.f + __expf(-(acc[jt][r] + xpv[jt][r])));
        float zg = 1.f / (1.f + __expf(-(acc[2 + jt][r] + xpv[2 + jt][r])));
        float ng = tanhf(xpv[4 + jt][r] + rg * (acc[4 + jt][r] + bhn));
        float hn = (1.f - zg) * ng + zg * hprev[jt][r];
        hprev[jt][r] = hn;
        u16 hq = f2bf(hn);
        hl[p ^ 1][bl][j] = hq;
        const int len = len4[r];
        const int tro = dir ? ((s < len) ? (len - 1 - s) : s) : s;
        outp[((size_t)(half * 16 + bl) * T + tro) * (2 * HH) + j] = hq;  // plain store, flies
      }
    }
    // one cheap barrier: LDS writes visible; global stores stay in flight
    asm volatile("s_waitcnt lgkmcnt(0)" ::: "memory");
    __builtin_amdgcn_s_barrier();
  }
  // carry f32 state to next chunk
#pragma unroll
  for (int jt = 0; jt < 2; ++jt)
#pragma unroll
    for (int r = 0; r < 4; ++r) {
      const int bl = khi * 4 + r;
      const int j = wv * 32 + jt * 16 + jl;
      h_state[(size_t)grp * 12288 + (size_t)j * 32 + half * 16 + bl] = hprev[jt][r];
    }
}

// ---------------- scores + row (q-axis) stats ----------------
__global__ __launch_bounds__(256) void k_scores(
    const u16* __restrict__ doc_h, const u16* __restrict__ q_h,
    const int* __restrict__ doc_lens, const int* __restrict__ q_lens,
    float* __restrict__ SM, float* __restrict__ rowmax, float* __restrict__ rowsum) {
  const int b = blockIdx.x >> 4, dblk = blockIdx.x & 15;
  const int tid = threadIdx.x, lane = tid & 63, wv = tid >> 6;
  const int col = lane & 15, khi = lane >> 4;
  const int dlen = doc_lens[b], qlen = q_lens[b];
  const u16* dp = doc_h + ((size_t)(b * DD + dblk * 64 + wv * 16 + col)) * (2 * HH) + khi * 8;
  const u16* qp = q_h + (size_t)b * QQ * (2 * HH);
  f32x4 acc[4];
#pragma unroll
  for (int nt = 0; nt < 4; ++nt) acc[nt] = f32x4{0.f, 0.f, 0.f, 0.f};
  for (int ks = 0; ks < 24; ++ks) {
    bf16x8 av = *(const bf16x8*)(dp + ks * 32);
#pragma unroll
    for (int nt = 0; nt < 4; ++nt) {
      bf16x8 bv = *(const bf16x8*)(qp + (size_t)(nt * 16 + col) * (2 * HH) + ks * 32 + khi * 8);
      acc[nt] = MFMA(av, bv, acc[nt]);
    }
  }
  const int d0 = dblk * 64 + wv * 16 + khi * 4;
  float* smb = SM + (size_t)b * DD * QQ;
#pragma unroll
  for (int r = 0; r < 4; ++r) {
    const int d = d0 + r;
    const bool dv = d < dlen;
    float v[4];
#pragma unroll
    for (int nt = 0; nt < 4; ++nt) {
      const int q = nt * 16 + col;
      v[nt] = (dv && q < qlen) ? acc[nt][r] : 0.f;
      smb[(size_t)d * QQ + q] = v[nt];
    }
    float mx = fmaxf(fmaxf(v[0], v[1]), fmaxf(v[2], v[3]));
#pragma unroll
    for (int off = 1; off < 16; off <<= 1) mx = fmaxf(mx, __shfl_xor(mx, off, 64));
    float sm = 0.f;
#pragma unroll
    for (int nt = 0; nt < 4; ++nt) {
      const int q = nt * 16 + col;
      if (dv && q < qlen) sm += __expf(v[nt] - mx);
    }
#pragma unroll
    for (int off = 1; off < 16; off <<= 1) sm += __shfl_xor(sm, off, 64);
    if (col == 0) { rowmax[b * DD + d] = mx; rowsum[b * DD + d] = sm; }
  }
}

// ---------------- column (d-axis) stats + beta_aver ----------------
__global__ __launch_bounds__(256) void k_cols(
    const float* __restrict__ SM, const float* __restrict__ rowmax, const float* __restrict__ rowsum,
    const int* __restrict__ doc_lens, const int* __restrict__ q_lens,
    float* __restrict__ colmax, float* __restrict__ colsum, float* __restrict__ bav) {
  const int b = blockIdx.x, tid = threadIdx.x;
  const int q = tid & 63, dg = tid >> 6;
  __shared__ float red[4][64];
  __shared__ float cmx[64];
  const float* smb = SM + (size_t)b * DD * QQ;
  float cm = -3.0e38f;
  for (int d = dg; d < DD; d += 4) cm = fmaxf(cm, smb[(size_t)d * QQ + q]);
  red[dg][q] = cm;
  __syncthreads();
  if (tid < 64) cmx[tid] = fmaxf(fmaxf(red[0][tid], red[1][tid]), fmaxf(red[2][tid], red[3][tid]));
  __syncthreads();
  const int dlen = doc_lens[b];
  const bool qv = q < q_lens[b];
  const float cmq = cmx[q];
  float cs = 0.f, ba = 0.f;
  for (int d = dg; d < DD; d += 4) {
    if (qv && d < dlen) {
      float v = smb[(size_t)d * QQ + q];
      cs += __expf(v - cmq);
      ba += __expf(v - rowmax[b * DD + d]) / (rowsum[b * DD + d] + EPSV);
    }
  }
  __syncthreads();
  red[dg][q] = cs;
  __syncthreads();
  float cst = 0.f;
  if (tid < 64) cst = red[0][tid] + red[1][tid] + red[2][tid] + red[3][tid];
  __syncthreads();
  red[dg][q] = ba;
  __syncthreads();
  if (tid < 64) {
    float bat = red[0][tid] + red[1][tid] + red[2][tid] + red[3][tid];
    colmax[b * QQ + tid] = cmx[tid];
    colsum[b * QQ + tid] = cst;
    bav[b * QQ + tid] = bat / (float)dlen;
  }
}

// ---------------- s = alpha @ beta_aver, probs, vocab scatter ----------------
__global__ __launch_bounds__(256) void k_s(
    const float* __restrict__ SM, const float* __restrict__ colmax, const float* __restrict__ colsum,
    const float* __restrict__ bav, const int* __restrict__ doc_lens, const int* __restrict__ q_lens,
    const int* __restrict__ documents, const int* __restrict__ answers,
    float* __restrict__ sc, float* __restrict__ cnt_tok, float* __restrict__ dout) {
  const int b = blockIdx.x >> 2, dblk = blockIdx.x & 3;
  const int tid = threadIdx.x;
  __shared__ float cm[64], cs[64], bv[64];
  __shared__ int qm[64];
  if (tid < 64) {
    cm[tid] = colmax[b * QQ + tid];
    cs[tid] = colsum[b * QQ + tid];
    bv[tid] = bav[b * QQ + tid];
    qm[tid] = (tid < q_lens[b]) ? 1 : 0;
  }
  __syncthreads();
  const int d = dblk * 256 + tid;
  const bool dv = d < doc_lens[b];
  const float* smr = SM + ((size_t)b * DD + d) * QQ;
  float sd = 0.f;
#pragma unroll
  for (int q = 0; q < 64; ++q) {
    float e = (dv && qm[q]) ? __expf(smr[q] - cm[q]) : 0.f;
    sd += e / (cs[q] + EPSV) * bv[q];
  }
  const int tok = documents[b * DD + d];
  if (tok == answers[b]) atomicAdd(&dout[b], sd);
  if (dv) {
    atomicAdd(&sc[(size_t)b * 50001 + tok], sd);
    atomicAdd(&cnt_tok[(size_t)b * 50001 + tok], 1.0f);
  }
}

// ---------------- first-max argmax over vocab ----------------
__global__ __launch_bounds__(256) void k_pred(
    const float* __restrict__ sc, const float* __restrict__ cnt_tok, float* __restrict__ dout) {
  const int b = blockIdx.x, tid = threadIdx.x;
  __shared__ float bvs[256];
  __shared__ int bis[256];
  float bvv = -3.0e38f;
  int bii = 0x7fffffff;
  for (int i = tid; i < 50001; i += 256) {
    if (cnt_tok[(size_t)b * 50001 + i] > 0.f) {
      float v = sc[(size_t)b * 50001 + i];
      if (v > bvv) { bvv = v; bii = i; }
    }
  }
  bvs[tid] = bvv;
  bis[tid] = bii;
  __syncthreads();
  for (int st = 128; st > 0; st >>= 1) {
    if (tid < st) {
      float v2 = bvs[tid + st];
      int i2 = bis[tid + st];
      if (v2 > bvs[tid] || (v2 == bvs[tid] && i2 < bis[tid])) { bvs[tid] = v2; bis[tid] = i2; }
    }
    __syncthreads();
  }
  if (tid == 0) dout[32 + b] = (float)bis[0];
}

extern "C" void kernel_launch(void* const* d_in, const int* in_sizes, int n_in,
                              void* d_out, int out_size, void* d_ws, size_t ws_size,
                              hipStream_t stream) {
  const int* documents = (const int*)d_in[0];
  const int* doc_lens = (const int*)d_in[1];
  const int* querys = (const int*)d_in[3];
  const int* query_lens = (const int*)d_in[4];
  const int* answers = (const int*)d_in[6];
  const float* emb = (const float*)d_in[7];
  const float* w_ih_f = (const float*)d_in[8];
  const float* w_hh_f = (const float*)d_in[9];
  const float* b_ih_f = (const float*)d_in[10];
  const float* b_hh_f = (const float*)d_in[11];
  const float* w_ih_b = (const float*)d_in[12];
  const float* w_hh_b = (const float*)d_in[13];
  const float* b_ih_b = (const float*)d_in[14];
  const float* b_hh_b = (const float*)d_in[15];
  float* dout = (float*)d_out;
  char* ws = (char*)d_ws;

  size_t o = 0;
  auto alloc = [&](size_t bytes) { size_t r = o; o += (bytes + 255) & ~(size_t)255; return r; };
  size_t o_embx = alloc((size_t)34816 * 384 * 2);
  size_t o_xpd  = alloc((size_t)2 * CH * 36864 * 4);   // 75.5 MB (doc chunk)
  size_t o_xpq  = alloc((size_t)2 * QQ * 36864 * 4);   // 18.9 MB (q full)
  size_t o_doch = alloc((size_t)NB * DD * 768 * 2);
  size_t o_qh   = alloc((size_t)NB * QQ * 768 * 2);
  size_t o_hst  = alloc((size_t)4 * HH * NB * 4);
  size_t o_SM   = alloc((size_t)NB * DD * QQ * 4);
  size_t o_rmax = alloc((size_t)NB * DD * 4);
  size_t o_rsum = alloc((size_t)NB * DD * 4);
  size_t o_cmax = alloc((size_t)NB * QQ * 4);
  size_t o_csum = alloc((size_t)NB * QQ * 4);
  size_t o_bav  = alloc((size_t)NB * QQ * 4);
  size_t o_sc   = alloc((size_t)NB * 50001 * 4);
  size_t o_ctk  = alloc((size_t)NB * 50001 * 4);
  (void)ws_size; (void)in_sizes; (void)n_in; (void)out_size;

  hipMemsetAsync(ws + o_sc, 0, (o_ctk - o_sc) + (size_t)NB * 50001 * 4, stream);
  hipMemsetAsync(d_out, 0, 64 * sizeof(float), stream);

  k_emb<<<13056, 256, 0, stream>>>(documents, querys, emb, (u16*)(ws + o_embx));
  for (int c = 0; c < 4; ++c) {
    const int cbase = c * CH;
    k_xp<<<c == 0 ? 60 : 48, 512, 0, stream>>>(
        (u16*)(ws + o_embx), doc_lens, query_lens,
        w_ih_f, b_ih_f, b_hh_f, w_ih_b, b_ih_b, b_hh_b,
        (float*)(ws + o_xpd), (float*)(ws + o_xpq), cbase);
    k_rec<<<c == 0 ? 8 : 4, 768, 0, stream>>>(
        (float*)(ws + o_xpd), (float*)(ws + o_xpq), doc_lens, query_lens,
        w_hh_f, b_hh_f, w_hh_b, b_hh_b,
        (u16*)(ws + o_doch), (u16*)(ws + o_qh),
        (float*)(ws + o_hst), cbase, c == 0 ? 1 : 0);
  }
  k_scores<<<512, 256, 0, stream>>>((u16*)(ws + o_doch), (u16*)(ws + o_qh), doc_lens, query_lens,
                                    (float*)(ws + o_SM), (float*)(ws + o_rmax), (float*)(ws + o_rsum));
  k_cols<<<32, 256, 0, stream>>>((float*)(ws + o_SM), (float*)(ws + o_rmax), (float*)(ws + o_rsum),
                                 doc_lens, query_lens,
                                 (float*)(ws + o_cmax), (float*)(ws + o_csum), (float*)(ws + o_bav));
  k_s<<<128, 256, 0, stream>>>((float*)(ws + o_SM), (float*)(ws + o_cmax), (float*)(ws + o_csum),
                               (float*)(ws + o_bav), doc_lens, query_lens, documents, answers,
                               (float*)(ws + o_sc), (float*)(ws + o_ctk), dout);
  k_pred<<<32, 256, 0, stream>>>((float*)(ws + o_sc), (float*)(ws + o_ctk), dout);
}